// Round 23
// baseline (236.797 us; speedup 1.0000x reference)
//
#include <hip/hip_runtime.h>

#define N0 262144
#define N1 16384
#define N2 1024
#define E0 409600
#define E1 20480
#define HD 128
#define PACK1 131072   // 1024*128
#define PACK2 65536    // 1024*64
#define BCAP 64        // bucket capacity (Poisson(25) tail past 64 ~ 1e-11)
#define PREP_BLOCKS 2448   // (PACK1+PACK2+E0+E1)/256 exactly

typedef __attribute__((ext_vector_type(8))) __bf16 bf16x8;
typedef __attribute__((ext_vector_type(4))) float f32x4;

__device__ __forceinline__ unsigned short f2bf(float f) {
    unsigned int u = __builtin_bit_cast(unsigned int, f);
    u += 0x7fffu + ((u >> 16) & 1u);
    return (unsigned short)(u >> 16);
}
__device__ __forceinline__ float bf2f(unsigned short h) {
    unsigned int u = ((unsigned int)h) << 16;
    return __builtin_bit_cast(float, u);
}

// ---- single-pass prep: pack V1/V2 + bucket-scatter both edge lists -------
__global__ __launch_bounds__(256) void prep_k(const float* __restrict__ V1,
                                              unsigned short* __restrict__ V1p,
                                              const float* __restrict__ V2,
                                              unsigned short* __restrict__ V2p,
                                              const int* __restrict__ src_ids,
                                              const int* __restrict__ e0s,
                                              const int* __restrict__ e0d,
                                              const int* __restrict__ e0t,
                                              const float* __restrict__ n0,
                                              int* __restrict__ cnt0,
                                              int2* __restrict__ rec0,
                                              const int* __restrict__ e1s,
                                              const int* __restrict__ e1d,
                                              const int* __restrict__ e1t,
                                              const float* __restrict__ n1,
                                              int* __restrict__ cnt1,
                                              int2* __restrict__ rec1) {
    int idx = blockIdx.x * 256 + threadIdx.x;
    if (idx < PACK1 + PACK2) {
        const float* V = idx < PACK1 ? V1 : V2;
        unsigned short* o = idx < PACK1 ? V1p : V2p;
        int NT = idx < PACK1 ? 8 : 4;
        int q = idx < PACK1 ? idx : idx - PACK1;
        int i  = q & 7;
        int l  = (q >> 3) & 63;
        int kt = (q >> 9) & 31;
        int nt = q >> 14;
        int k = kt * 32 + (l >> 4) * 8 + i;
        int j = nt * 16 + (l & 15);
        o[q] = f2bf(V[(size_t)k * (NT * 16) + j]);
    } else if (idx < PACK1 + PACK2 + E0) {
        int e = idx - (PACK1 + PACK2);
        int d = e0d[e];
        int slot = atomicAdd(&cnt0[d], 1);
        if (slot < BCAP)
            rec0[(size_t)d * BCAP + slot] =
                make_int2(src_ids[e0s[e]] | (e0t[e] << 24),
                          __builtin_bit_cast(int, n0[e]));
    } else {
        int e = idx - (PACK1 + PACK2 + E0);
        int d = e1d[e];
        int slot = atomicAdd(&cnt1[d], 1);
        if (slot < BCAP)
            rec1[(size_t)d * BCAP + slot] =
                make_int2(e1s[e] | (e1t[e] << 24),
                          __builtin_bit_cast(int, n1[e]));
    }
}

// ---- per-bucket aggregation, synchronous chunk-8 (fused1 only) -----------
template <bool L0>
__device__ __forceinline__ void agg_bucket8(const int2* __restrict__ bucket, int n,
                                            const float* __restrict__ compS,
                                            const float* __restrict__ xf,
                                            const unsigned short* __restrict__ xh,
                                            int lane, float* acc) {
#pragma unroll
    for (int i = 0; i < 16; i++) acc[i] = 0.f;
    if (n <= 0) return;
    const int last = n - 1;

    auto ldx = [&](int2 r) -> float2 {
        int s = r.x & 0xFFFFFF;
        if constexpr (L0) {
            return *(const float2*)(xf + (size_t)s * HD + lane * 2);
        } else {
            unsigned int u = *(const unsigned int*)(xh + (size_t)s * HD + lane * 2);
            return make_float2(bf2f((unsigned short)(u & 0xffffu)),
                               bf2f((unsigned short)(u >> 16)));
        }
    };
    auto consume = [&](int2 r, float2 x, bool valid) {
        float nrm = valid ? __builtin_bit_cast(float, r.y) : 0.f;
        const float* cp = compS + ((unsigned)r.x >> 24) * 8;
        float4 c0 = *(const float4*)cp;
        float4 c1 = *(const float4*)(cp + 4);
        float xx = x.x * nrm, xy = x.y * nrm;
        acc[0]  += c0.x * xx; acc[1]  += c0.x * xy;
        acc[2]  += c0.y * xx; acc[3]  += c0.y * xy;
        acc[4]  += c0.z * xx; acc[5]  += c0.z * xy;
        acc[6]  += c0.w * xx; acc[7]  += c0.w * xy;
        acc[8]  += c1.x * xx; acc[9]  += c1.x * xy;
        acc[10] += c1.y * xx; acc[11] += c1.y * xy;
        acc[12] += c1.z * xx; acc[13] += c1.z * xy;
        acc[14] += c1.w * xx; acc[15] += c1.w * xy;
    };

    for (int e = 0; e <= last; e += 8) {
        int2 r0 = bucket[e];
        int2 r1 = bucket[e + 1 <= last ? e + 1 : last];
        int2 r2 = bucket[e + 2 <= last ? e + 2 : last];
        int2 r3 = bucket[e + 3 <= last ? e + 3 : last];
        int2 r4 = bucket[e + 4 <= last ? e + 4 : last];
        int2 r5 = bucket[e + 5 <= last ? e + 5 : last];
        int2 r6 = bucket[e + 6 <= last ? e + 6 : last];
        int2 r7 = bucket[e + 7 <= last ? e + 7 : last];
        float2 x0 = ldx(r0);
        float2 x1 = ldx(r1);
        float2 x2 = ldx(r2);
        float2 x3 = ldx(r3);
        float2 x4 = ldx(r4);
        float2 x5 = ldx(r5);
        float2 x6 = ldx(r6);
        float2 x7 = ldx(r7);
        consume(r0, x0, true);
        consume(r1, x1, e + 1 <= last);
        consume(r2, x2, e + 2 <= last);
        consume(r3, x3, e + 3 <= last);
        consume(r4, x4, e + 4 <= last);
        consume(r5, x5, e + 5 <= last);
        consume(r6, x6, e + 6 <= last);
        consume(r7, x7, e + 7 <= last);
    }
}

// write one aggregated row into the swizzled LDS A-tile (row stride 2048 B)
__device__ __forceinline__ void write_lds_row(unsigned short* aT, int v, int lane,
                                              const float* acc) {
#pragma unroll
    for (int b = 0; b < 8; b++) {
        unsigned int o = (unsigned int)f2bf(acc[2 * b]) | ((unsigned int)f2bf(acc[2 * b + 1]) << 16);
        int chunk = b * 16 + (lane >> 2);
        int swc = chunk ^ (v & 15);
        *(unsigned int*)((char*)aT + (size_t)v * 2048 + swc * 16 + (lane & 3) * 4) = o;
    }
}

// ---- fused layer 0: BISECT — R22 staging + SCALAR consume from LDS -------
// Validates cA/xB staging + aT-write + sync independent of MFMA fragments.
__global__ __launch_bounds__(512) void fused0_k(const int* __restrict__ cnt,
                                                const int2* __restrict__ rec,
                                                const float* __restrict__ comp,
                                                const float* __restrict__ emb,
                                                const unsigned short* __restrict__ Bp,
                                                const float* __restrict__ bias,
                                                unsigned short* __restrict__ hbf) {
    __shared__ unsigned short aT[16 * 1024];   // 32 KB
    __shared__ unsigned short xB[64 * 128];    // 16 KB  x rows, B-frag layout
    __shared__ unsigned short cA[1024];        // 2 KB   coef, A-frag layout
    __shared__ float compS[512];               // 2 KB
    const int t = threadIdx.x;
    const int w = t >> 6, lane = t & 63;
    const int row0 = blockIdx.x * 16;
    compS[t] = comp[t];
    __syncthreads();

    const int bb = t >> 6;        // basis 0..7
    const int chg = t & 63;       // channel group: handles chg and chg+64

    for (int s = 0; s < 16; s++) {
        const int v = row0 + s;
        const int n = min(cnt[v], BCAP);
        const int2* recV = rec + (size_t)v * BCAP;
        __syncthreads();                        // prev dst's consume done

        // stage coef A-frag (R22): element (b,k) at ((k>>3)*16 + b)*8 + (k&7)
        {
            const int b = t & 15;
            const int k0 = t >> 4;              // 0..31
#pragma unroll
            for (int j = 0; j < 2; j++) {
                int k = j * 32 + k0;
                unsigned short cv = 0;
                if (b < 8 && k < n) {
                    int2 rc = recV[k];
                    float nrm = __builtin_bit_cast(float, rc.y);
                    cv = f2bf(compS[((unsigned)rc.x >> 24) * 8 + b] * nrm);
                }
                cA[((k >> 3) * 16 + b) * 8 + (k & 7)] = cv;
            }
        }
        // stage x rows -> xB (R22): element (k,ch) at ((k>>3)*128 + ch)*8 + (k&7)
#pragma unroll
        for (int j = 0; j < 8; j++) {
            int k = w * 8 + j;                  // wave-uniform predicate
            if (k < n) {
                int src = recV[k].x & 0xFFFFFF;
                float2 xv = *(const float2*)(emb + (size_t)src * HD + lane * 2);
                int ch = lane * 2;
                int base = (k >> 3) * 128;
                int kl = k & 7;
                xB[(base + ch) * 8 + kl]     = f2bf(xv.x);
                xB[(base + ch + 1) * 8 + kl] = f2bf(xv.y);
            }
        }
        __syncthreads();                        // staging visible to all

        // scalar consume straight from staged buffers (layout-independent math)
        float a0 = 0.f, a1 = 0.f;
        for (int k = 0; k < n; k++) {
            float cv = bf2f(cA[((k >> 3) * 16 + bb) * 8 + (k & 7)]);
            float x0 = bf2f(xB[((k >> 3) * 128 + chg) * 8 + (k & 7)]);
            float x1 = bf2f(xB[((k >> 3) * 128 + chg + 64) * 8 + (k & 7)]);
            a0 += cv * x0;
            a1 += cv * x1;
        }
        // aT write (R22 formula; equals write_lds_row addressing)
        {
            int kk0 = bb * 128 + chg;
            *(unsigned short*)((char*)aT + s * 2048 +
                (((kk0 >> 3) ^ s) * 16) + (kk0 & 7) * 2) = f2bf(a0);
            int kk1 = kk0 + 64;
            *(unsigned short*)((char*)aT + s * 2048 +
                (((kk1 >> 3) ^ s) * 16) + (kk1 & 7) * 2) = f2bf(a1);
        }
    }
    __syncthreads();

    // GEMM phase (R20 exact): C[16,128] = aT @ V1p + b1, ReLU -> hbf
    const int rl = lane & 15, g = lane >> 4;
    f32x4 c0 = (f32x4){0.f, 0.f, 0.f, 0.f};
#pragma unroll 4
    for (int kidx = 0; kidx < 32; kidx++) {
        bf16x8 bfr = *(const bf16x8*)(Bp + (((size_t)w * 32 + kidx) * 64 + lane) * 8);
        int ch = kidx * 4 + g;
        bf16x8 a0 = *(const bf16x8*)((const char*)aT + (size_t)rl * 2048 + (size_t)((ch ^ rl) * 16));
        c0 = __builtin_amdgcn_mfma_f32_16x16x32_bf16(a0, bfr, c0, 0, 0, 0);
    }
    int col = w * 16 + rl;
    float bv = bias[col];
#pragma unroll
    for (int q = 0; q < 4; q++) {
        int r0 = row0 + g * 4 + q;
        float v0 = c0[q] + bv;
        v0 = v0 > 0.f ? v0 : 0.f;
        hbf[(size_t)r0 * 128 + col] = f2bf(v0);
    }
}

// ---- fused layer 1: 16-row tile; 2 rows/wave; K-split MFMA @V2p -> out ---
__global__ __launch_bounds__(512) void fused1_k(const int* __restrict__ cnt,
                                                const int2* __restrict__ rec,
                                                const float* __restrict__ comp,
                                                const unsigned short* __restrict__ hbf,
                                                const unsigned short* __restrict__ Bp,
                                                const float* __restrict__ bias,
                                                float* __restrict__ out) {
    __shared__ unsigned short aT[16 * 1024];   // 32 KB
    __shared__ f32x4 red[8 * 64];              // 8 KB partial C
    __shared__ float compS[512];               // 2 KB
    const int t = threadIdx.x;
    const int w = t >> 6, lane = t & 63;
    const int row0 = blockIdx.x * 16;
    compS[t] = comp[t];
    __syncthreads();
    float acc[16];
    int va = row0 + w * 2;
    int na = min(cnt[va], BCAP);
    agg_bucket8<false>(rec + (size_t)va * BCAP, na, compS, nullptr, hbf, lane, acc);
    write_lds_row(aT, w * 2, lane, acc);
    int vb = va + 1;
    int nb = min(cnt[vb], BCAP);
    agg_bucket8<false>(rec + (size_t)vb * BCAP, nb, compS, nullptr, hbf, lane, acc);
    write_lds_row(aT, w * 2 + 1, lane, acc);
    __syncthreads();
    const int kh = w >> 2, nt = w & 3;
    const int rl = lane & 15, g = lane >> 4;
    f32x4 c = (f32x4){0.f, 0.f, 0.f, 0.f};
#pragma unroll 4
    for (int k = 0; k < 16; k++) {
        int kidx = kh * 16 + k;
        bf16x8 bfr = *(const bf16x8*)(Bp + (((size_t)nt * 32 + kidx) * 64 + lane) * 8);
        int ch = kidx * 4 + g;
        bf16x8 a0 = *(const bf16x8*)((const char*)aT + (size_t)rl * 2048 + (size_t)((ch ^ rl) * 16));
        c = __builtin_amdgcn_mfma_f32_16x16x32_bf16(a0, bfr, c, 0, 0, 0);
    }
    red[w * 64 + lane] = c;
    __syncthreads();
    if (w < 4) {
        f32x4 a = red[w * 64 + lane];
        f32x4 b = red[(w + 4) * 64 + lane];
        int col = nt * 16 + rl;
        float bv = bias[col];
#pragma unroll
        for (int q = 0; q < 4; q++) {
            int r0 = row0 + g * 4 + q;
            out[(size_t)r0 * 64 + col] = a[q] + b[q] + bv;
        }
    }
}

extern "C" void kernel_launch(void* const* d_in, const int* in_sizes, int n_in,
                              void* d_out, int out_size, void* d_ws, size_t ws_size,
                              hipStream_t stream) {
    const int*   src_ids = (const int*)d_in[0];
    const int*   e0_src  = (const int*)d_in[1];
    const int*   e0_dst  = (const int*)d_in[2];
    const int*   e0_type = (const int*)d_in[3];
    const float* norm0   = (const float*)d_in[4];
    const int*   e1_src  = (const int*)d_in[5];
    const int*   e1_dst  = (const int*)d_in[6];
    const int*   e1_type = (const int*)d_in[7];
    const float* norm1   = (const float*)d_in[8];
    const float* emb     = (const float*)d_in[9];
    const float* V1      = (const float*)d_in[10];
    const float* comp1   = (const float*)d_in[11];
    const float* b1      = (const float*)d_in[12];
    const float* V2      = (const float*)d_in[13];
    const float* comp2   = (const float*)d_in[14];
    const float* b2      = (const float*)d_in[15];
    float* out = (float*)d_out;

    char* base = (char*)d_ws;
    size_t off = 0;
    auto alloc = [&](size_t bytes) -> char* {
        off = (off + 255) & ~(size_t)255;
        char* r = base + off;
        off += bytes;
        return r;
    };
    unsigned short* hbf = (unsigned short*)alloc((size_t)N1 * HD * 2);
    unsigned short* V1p = (unsigned short*)alloc((size_t)1024 * 128 * 2);
    unsigned short* V2p = (unsigned short*)alloc((size_t)1024 * 64 * 2);
    int*   cnt    = (int*)alloc((size_t)(N1 + N2) * 4);
    int*   cnt0   = cnt;
    int*   cnt1   = cnt + N1;
    int2*  rec0   = (int2*)alloc((size_t)N1 * BCAP * 8);   // 8 MB
    int2*  rec1   = (int2*)alloc((size_t)N2 * BCAP * 8);   // 0.5 MB
    (void)ws_size; (void)in_sizes; (void)n_in; (void)out_size;

    hipMemsetAsync(cnt, 0, (size_t)(N1 + N2) * 4, stream);

    prep_k<<<PREP_BLOCKS, 256, 0, stream>>>(V1, V1p, V2, V2p,
                                            src_ids, e0_src, e0_dst, e0_type, norm0,
                                            cnt0, rec0,
                                            e1_src, e1_dst, e1_type, norm1,
                                            cnt1, rec1);
    fused0_k<<<N1 / 16, 512, 0, stream>>>(cnt0, rec0, comp1, emb, V1p, b1, hbf);
    fused1_k<<<N2 / 16, 512, 0, stream>>>(cnt1, rec1, comp2, hbf, V2p, b2, out);
}

// Round 24
// 90.332 us; speedup vs baseline: 2.6214x; 2.6214x over previous
//
#include <hip/hip_runtime.h>

#define N0 262144
#define N1 16384
#define N2 1024
#define E0 409600
#define E1 20480
#define HD 128
#define PACK1 131072   // 1024*128
#define PACK2 65536    // 1024*64
#define BCAP 64        // bucket capacity (Poisson(25) tail past 64 ~ 1e-11)
#define PREP_BLOCKS 2448   // (PACK1+PACK2+E0+E1)/256 exactly

typedef __attribute__((ext_vector_type(8))) __bf16 bf16x8;
typedef __attribute__((ext_vector_type(4))) float f32x4;

// async global->LDS: 64 lanes x 4B; LDS dest uniform, global addr per-lane
#define GLD4(g, l) __builtin_amdgcn_global_load_lds(                        \
    (const __attribute__((address_space(1))) void*)(g),                     \
    (__attribute__((address_space(3))) void*)(l), 4, 0, 0)

__device__ __forceinline__ unsigned short f2bf(float f) {
    unsigned int u = __builtin_bit_cast(unsigned int, f);
    u += 0x7fffu + ((u >> 16) & 1u);
    return (unsigned short)(u >> 16);
}
__device__ __forceinline__ float bf2f(unsigned short h) {
    unsigned int u = ((unsigned int)h) << 16;
    return __builtin_bit_cast(float, u);
}

// ---- single-pass prep: coalesced V-pack + bucket-scatter both edge lists -
// V-pack: tid -> (k,j) with j fast => V reads perfectly coalesced; the
// B-fragment index q(k,j) is the exact inverse of the old q->(k,j) decode.
__global__ __launch_bounds__(256) void prep_k(const float* __restrict__ V1,
                                              unsigned short* __restrict__ V1p,
                                              const float* __restrict__ V2,
                                              unsigned short* __restrict__ V2p,
                                              const int* __restrict__ src_ids,
                                              const int* __restrict__ e0s,
                                              const int* __restrict__ e0d,
                                              const int* __restrict__ e0t,
                                              const float* __restrict__ n0,
                                              int* __restrict__ cnt0,
                                              int2* __restrict__ rec0,
                                              const int* __restrict__ e1s,
                                              const int* __restrict__ e1d,
                                              const int* __restrict__ e1t,
                                              const float* __restrict__ n1,
                                              int* __restrict__ cnt1,
                                              int2* __restrict__ rec1) {
    int idx = blockIdx.x * 256 + threadIdx.x;
    if (idx < PACK1) {
        int k = idx >> 7, j = idx & 127;       // idx = k*128 + j (row-major V1)
        int q = (((j >> 4) * 32 + (k >> 5)) * 64 + ((k & 31) >> 3) * 16 + (j & 15)) * 8 + (k & 7);
        V1p[q] = f2bf(V1[idx]);
    } else if (idx < PACK1 + PACK2) {
        int r = idx - PACK1;
        int k = r >> 6, j = r & 63;            // r = k*64 + j (row-major V2)
        int q = (((j >> 4) * 32 + (k >> 5)) * 64 + ((k & 31) >> 3) * 16 + (j & 15)) * 8 + (k & 7);
        V2p[q] = f2bf(V2[r]);
    } else if (idx < PACK1 + PACK2 + E0) {
        int e = idx - (PACK1 + PACK2);
        int d = e0d[e];
        int slot = atomicAdd(&cnt0[d], 1);
        if (slot < BCAP)
            rec0[(size_t)d * BCAP + slot] =
                make_int2(src_ids[e0s[e]] | (e0t[e] << 24),
                          __builtin_bit_cast(int, n0[e]));
    } else {
        int e = idx - (PACK1 + PACK2 + E0);
        int d = e1d[e];
        int slot = atomicAdd(&cnt1[d], 1);
        if (slot < BCAP)
            rec1[(size_t)d * BCAP + slot] =
                make_int2(e1s[e] | (e1t[e] << 24),
                          __builtin_bit_cast(int, n1[e]));
    }
}

// ---- per-bucket aggregation, synchronous chunk-8 (fused1 only) -----------
template <bool L0>
__device__ __forceinline__ void agg_bucket8(const int2* __restrict__ bucket, int n,
                                            const float* __restrict__ compS,
                                            const float* __restrict__ xf,
                                            const unsigned short* __restrict__ xh,
                                            int lane, float* acc) {
#pragma unroll
    for (int i = 0; i < 16; i++) acc[i] = 0.f;
    if (n <= 0) return;
    const int last = n - 1;

    auto ldx = [&](int2 r) -> float2 {
        int s = r.x & 0xFFFFFF;
        if constexpr (L0) {
            return *(const float2*)(xf + (size_t)s * HD + lane * 2);
        } else {
            unsigned int u = *(const unsigned int*)(xh + (size_t)s * HD + lane * 2);
            return make_float2(bf2f((unsigned short)(u & 0xffffu)),
                               bf2f((unsigned short)(u >> 16)));
        }
    };
    auto consume = [&](int2 r, float2 x, bool valid) {
        float nrm = valid ? __builtin_bit_cast(float, r.y) : 0.f;
        const float* cp = compS + ((unsigned)r.x >> 24) * 8;
        float4 c0 = *(const float4*)cp;
        float4 c1 = *(const float4*)(cp + 4);
        float xx = x.x * nrm, xy = x.y * nrm;
        acc[0]  += c0.x * xx; acc[1]  += c0.x * xy;
        acc[2]  += c0.y * xx; acc[3]  += c0.y * xy;
        acc[4]  += c0.z * xx; acc[5]  += c0.z * xy;
        acc[6]  += c0.w * xx; acc[7]  += c0.w * xy;
        acc[8]  += c1.x * xx; acc[9]  += c1.x * xy;
        acc[10] += c1.y * xx; acc[11] += c1.y * xy;
        acc[12] += c1.z * xx; acc[13] += c1.z * xy;
        acc[14] += c1.w * xx; acc[15] += c1.w * xy;
    };

    for (int e = 0; e <= last; e += 8) {
        int2 r0 = bucket[e];
        int2 r1 = bucket[e + 1 <= last ? e + 1 : last];
        int2 r2 = bucket[e + 2 <= last ? e + 2 : last];
        int2 r3 = bucket[e + 3 <= last ? e + 3 : last];
        int2 r4 = bucket[e + 4 <= last ? e + 4 : last];
        int2 r5 = bucket[e + 5 <= last ? e + 5 : last];
        int2 r6 = bucket[e + 6 <= last ? e + 6 : last];
        int2 r7 = bucket[e + 7 <= last ? e + 7 : last];
        float2 x0 = ldx(r0);
        float2 x1 = ldx(r1);
        float2 x2 = ldx(r2);
        float2 x3 = ldx(r3);
        float2 x4 = ldx(r4);
        float2 x5 = ldx(r5);
        float2 x6 = ldx(r6);
        float2 x7 = ldx(r7);
        consume(r0, x0, true);
        consume(r1, x1, e + 1 <= last);
        consume(r2, x2, e + 2 <= last);
        consume(r3, x3, e + 3 <= last);
        consume(r4, x4, e + 4 <= last);
        consume(r5, x5, e + 5 <= last);
        consume(r6, x6, e + 6 <= last);
        consume(r7, x7, e + 7 <= last);
    }
}

// write one aggregated row into the swizzled LDS A-tile (row stride 2048 B)
__device__ __forceinline__ void write_lds_row(unsigned short* aT, int v, int lane,
                                              const float* acc) {
#pragma unroll
    for (int b = 0; b < 8; b++) {
        unsigned int o = (unsigned int)f2bf(acc[2 * b]) | ((unsigned int)f2bf(acc[2 * b + 1]) << 16);
        int chunk = b * 16 + (lane >> 2);
        int swc = chunk ^ (v & 15);
        *(unsigned int*)((char*)aT + (size_t)v * 2048 + swc * 16 + (lane & 3) * 4) = o;
    }
}

// ---- fused layer 0: queue-balanced async-DMA gather agg + MFMA @V1p ------
__global__ __launch_bounds__(512) void fused0_k(const int* __restrict__ cnt,
                                                const int2* __restrict__ rec,
                                                const float* __restrict__ comp,
                                                const float* __restrict__ emb,
                                                const unsigned short* __restrict__ Bp,
                                                const float* __restrict__ bias,
                                                unsigned short* __restrict__ hbf) {
    __shared__ unsigned short aT[16 * 1024];   // 32 KB
    __shared__ float compS[512];               // 2 KB
    __shared__ int2  ldsRec[8][64];            // 4 KB  (per-wave: current bucket)
    __shared__ float ldsX[8][2][4][HD];        // 32 KB (per-wave: 2 slots x 4 rows)
    __shared__ int qctr;                       // bucket work queue
    const int t = threadIdx.x;
    const int w = t >> 6, lane = t & 63;
    const int row0 = blockIdx.x * 16;
    compS[t] = comp[t];
    if (t == 0) qctr = 0;
    __syncthreads();

    const float* gemb = emb + lane;
    float acc[16];
    for (;;) {
        int slot;
        if (lane == 0) slot = atomicAdd(&qctr, 1);
        slot = __builtin_amdgcn_readfirstlane(slot);
        if (slot >= 16) break;

        const int v = row0 + slot;
        const int n = min(cnt[v], BCAP);

        // stage this bucket's 64 recs (512 B contiguous) into LDS via DMA
        {
            const float* gr = (const float*)(rec + (size_t)v * BCAP);
            float* lr = (float*)ldsRec[w];
            GLD4(gr + lane, lr);
            GLD4(gr + 64 + lane, lr + 64);
            asm volatile("s_waitcnt vmcnt(0)" ::: "memory");
            __builtin_amdgcn_sched_barrier(0);
        }
        // zero-pad to a multiple of 4 (src=0, norm=0): clamp-free loop
        {
            int pa = (4 - (n & 3)) & 3;
            if (lane < pa) ldsRec[w][n + lane] = make_int2(0, 0);
        }

        const int2* recB = ldsRec[w];
#pragma unroll
        for (int i = 0; i < 16; i++) acc[i] = 0.f;
        if (n > 0) {
            const int nc = (n + 3) >> 2;
            auto issue = [&](int c, int s) {
#pragma unroll
                for (int r = 0; r < 4; r++) {
                    int src = recB[c * 4 + r].x & 0xFFFFFF;
                    const float* g = gemb + (size_t)src * HD;
                    float* l = &ldsX[w][s][r][0];
                    GLD4(g, l);            // chans 0..63
                    GLD4(g + 64, l + 64);  // chans 64..127
                }
            };
            auto consume = [&](int c, int s) {
#pragma unroll
                for (int r = 0; r < 4; r++) {
                    int2 rc = recB[c * 4 + r];
                    float nrm = __builtin_bit_cast(float, rc.y);
                    const float* cp = compS + ((unsigned)rc.x >> 24) * 8;
                    float4 c0 = *(const float4*)cp;
                    float4 c1 = *(const float4*)(cp + 4);
                    float2 x = *(const float2*)&ldsX[w][s][r][lane * 2];
                    float xx = x.x * nrm, xy = x.y * nrm;
                    acc[0]  += c0.x * xx; acc[1]  += c0.x * xy;
                    acc[2]  += c0.y * xx; acc[3]  += c0.y * xy;
                    acc[4]  += c0.z * xx; acc[5]  += c0.z * xy;
                    acc[6]  += c0.w * xx; acc[7]  += c0.w * xy;
                    acc[8]  += c1.x * xx; acc[9]  += c1.x * xy;
                    acc[10] += c1.y * xx; acc[11] += c1.y * xy;
                    acc[12] += c1.z * xx; acc[13] += c1.z * xy;
                    acc[14] += c1.w * xx; acc[15] += c1.w * xy;
                }
            };
            issue(0, 0);
            if (nc > 1) issue(1, 1);
            for (int c = 0; c < nc; c++) {
                if (c + 1 < nc) { asm volatile("s_waitcnt vmcnt(8)" ::: "memory"); }
                else            { asm volatile("s_waitcnt vmcnt(0)" ::: "memory"); }
                __builtin_amdgcn_sched_barrier(0);
                consume(c, c & 1);
                if (c + 2 < nc) issue(c + 2, c & 1);
            }
        }
        write_lds_row(aT, slot, lane, acc);
    }
    __syncthreads();

    const int rl = lane & 15, g = lane >> 4;
    f32x4 c0 = (f32x4){0.f, 0.f, 0.f, 0.f};
#pragma unroll 4
    for (int kidx = 0; kidx < 32; kidx++) {
        bf16x8 bfr = *(const bf16x8*)(Bp + (((size_t)w * 32 + kidx) * 64 + lane) * 8);
        int ch = kidx * 4 + g;
        bf16x8 a0 = *(const bf16x8*)((const char*)aT + (size_t)rl * 2048 + (size_t)((ch ^ rl) * 16));
        c0 = __builtin_amdgcn_mfma_f32_16x16x32_bf16(a0, bfr, c0, 0, 0, 0);
    }
    int col = w * 16 + rl;
    float bv = bias[col];
#pragma unroll
    for (int q = 0; q < 4; q++) {
        int r0 = row0 + g * 4 + q;
        float v0 = c0[q] + bv;
        v0 = v0 > 0.f ? v0 : 0.f;
        hbf[(size_t)r0 * 128 + col] = f2bf(v0);
    }
}

// ---- fused layer 1: 16-row tile; 2 rows/wave; K-split MFMA @V2p -> out ---
__global__ __launch_bounds__(512) void fused1_k(const int* __restrict__ cnt,
                                                const int2* __restrict__ rec,
                                                const float* __restrict__ comp,
                                                const unsigned short* __restrict__ hbf,
                                                const unsigned short* __restrict__ Bp,
                                                const float* __restrict__ bias,
                                                float* __restrict__ out) {
    __shared__ unsigned short aT[16 * 1024];   // 32 KB
    __shared__ f32x4 red[8 * 64];              // 8 KB partial C
    __shared__ float compS[512];               // 2 KB
    const int t = threadIdx.x;
    const int w = t >> 6, lane = t & 63;
    const int row0 = blockIdx.x * 16;
    compS[t] = comp[t];
    __syncthreads();
    float acc[16];
    int va = row0 + w * 2;
    int na = min(cnt[va], BCAP);
    agg_bucket8<false>(rec + (size_t)va * BCAP, na, compS, nullptr, hbf, lane, acc);
    write_lds_row(aT, w * 2, lane, acc);
    int vb = va + 1;
    int nb = min(cnt[vb], BCAP);
    agg_bucket8<false>(rec + (size_t)vb * BCAP, nb, compS, nullptr, hbf, lane, acc);
    write_lds_row(aT, w * 2 + 1, lane, acc);
    __syncthreads();
    const int kh = w >> 2, nt = w & 3;
    const int rl = lane & 15, g = lane >> 4;
    f32x4 c = (f32x4){0.f, 0.f, 0.f, 0.f};
#pragma unroll 4
    for (int k = 0; k < 16; k++) {
        int kidx = kh * 16 + k;
        bf16x8 bfr = *(const bf16x8*)(Bp + (((size_t)nt * 32 + kidx) * 64 + lane) * 8);
        int ch = kidx * 4 + g;
        bf16x8 a0 = *(const bf16x8*)((const char*)aT + (size_t)rl * 2048 + (size_t)((ch ^ rl) * 16));
        c = __builtin_amdgcn_mfma_f32_16x16x32_bf16(a0, bfr, c, 0, 0, 0);
    }
    red[w * 64 + lane] = c;
    __syncthreads();
    if (w < 4) {
        f32x4 a = red[w * 64 + lane];
        f32x4 b = red[(w + 4) * 64 + lane];
        int col = nt * 16 + rl;
        float bv = bias[col];
#pragma unroll
        for (int q = 0; q < 4; q++) {
            int r0 = row0 + g * 4 + q;
            out[(size_t)r0 * 64 + col] = a[q] + b[q] + bv;
        }
    }
}

extern "C" void kernel_launch(void* const* d_in, const int* in_sizes, int n_in,
                              void* d_out, int out_size, void* d_ws, size_t ws_size,
                              hipStream_t stream) {
    const int*   src_ids = (const int*)d_in[0];
    const int*   e0_src  = (const int*)d_in[1];
    const int*   e0_dst  = (const int*)d_in[2];
    const int*   e0_type = (const int*)d_in[3];
    const float* norm0   = (const float*)d_in[4];
    const int*   e1_src  = (const int*)d_in[5];
    const int*   e1_dst  = (const int*)d_in[6];
    const int*   e1_type = (const int*)d_in[7];
    const float* norm1   = (const float*)d_in[8];
    const float* emb     = (const float*)d_in[9];
    const float* V1      = (const float*)d_in[10];
    const float* comp1   = (const float*)d_in[11];
    const float* b1      = (const float*)d_in[12];
    const float* V2      = (const float*)d_in[13];
    const float* comp2   = (const float*)d_in[14];
    const float* b2      = (const float*)d_in[15];
    float* out = (float*)d_out;

    char* base = (char*)d_ws;
    size_t off = 0;
    auto alloc = [&](size_t bytes) -> char* {
        off = (off + 255) & ~(size_t)255;
        char* r = base + off;
        off += bytes;
        return r;
    };
    unsigned short* hbf = (unsigned short*)alloc((size_t)N1 * HD * 2);
    unsigned short* V1p = (unsigned short*)alloc((size_t)1024 * 128 * 2);
    unsigned short* V2p = (unsigned short*)alloc((size_t)1024 * 64 * 2);
    int*   cnt    = (int*)alloc((size_t)(N1 + N2) * 4);
    int*   cnt0   = cnt;
    int*   cnt1   = cnt + N1;
    int2*  rec0   = (int2*)alloc((size_t)N1 * BCAP * 8);   // 8 MB
    int2*  rec1   = (int2*)alloc((size_t)N2 * BCAP * 8);   // 0.5 MB
    (void)ws_size; (void)in_sizes; (void)n_in; (void)out_size;

    hipMemsetAsync(cnt, 0, (size_t)(N1 + N2) * 4, stream);

    prep_k<<<PREP_BLOCKS, 256, 0, stream>>>(V1, V1p, V2, V2p,
                                            src_ids, e0_src, e0_dst, e0_type, norm0,
                                            cnt0, rec0,
                                            e1_src, e1_dst, e1_type, norm1,
                                            cnt1, rec1);
    fused0_k<<<N1 / 16, 512, 0, stream>>>(cnt0, rec0, comp1, emb, V1p, b1, hbf);
    fused1_k<<<N2 / 16, 512, 0, stream>>>(cnt1, rec1, comp2, hbf, V2p, b2, out);
}